// Round 1
// baseline (571.740 us; speedup 1.0000x reference)
//
#include <hip/hip_runtime.h>
#include <math.h>

#define B_     8
#define NCOIL  16
#define H_     384
#define W_     384
#define HW     (H_*W_)
#define STRIPS 16
#define ROWS_PER (H_/STRIPS)

// ws layout (floats):
//   [0, 3888)            Cacc[b][6][81]  pair order: x0e, x1e, x0x0, x0x1, x1x1, ee
//   [3888, 4176)         G[b][2][2][9]
//   [4224, 4224+2359296) ximg[b][2][HW]
#define WS_CACC 0
#define WS_G    3888
#define WS_XIMG 4224

// ---------------- Pass A: coil-combine  ximg = sum_c x * conj(sens) ----------
__global__ void ka_coil_reduce(const float* __restrict__ x,
                               const float* __restrict__ sens,
                               float* __restrict__ ws) {
    int b = blockIdx.y;
    int t = blockIdx.x * blockDim.x + threadIdx.x;   // pixel-pair index
    // block 0 of each b also zeroes that b's correlation accumulators
    if (blockIdx.x == 0) {
        for (int i = threadIdx.x; i < 6*81; i += blockDim.x)
            ws[WS_CACC + b*6*81 + i] = 0.f;
    }
    if (t >= HW/2) return;
    const float4* xp = (const float4*)(x    + (size_t)b*NCOIL*HW*2);
    const float4* sp = (const float4*)(sens + (size_t)b*NCOIL*HW*2);
    float re0=0.f, im0=0.f, re1=0.f, im1=0.f;
    #pragma unroll 4
    for (int c = 0; c < NCOIL; ++c) {
        float4 xv = xp[(size_t)c*(HW/2) + t];
        float4 sv = sp[(size_t)c*(HW/2) + t];
        re0 += xv.x*sv.x + xv.y*sv.y;      // x * conj(s): re
        im0 += xv.y*sv.x - xv.x*sv.y;      // im
        re1 += xv.z*sv.z + xv.w*sv.w;
        im1 += xv.w*sv.z - xv.z*sv.w;
    }
    float* x0 = ws + WS_XIMG + ((size_t)b*2+0)*HW;
    float* x1 = ws + WS_XIMG + ((size_t)b*2+1)*HW;
    ((float2*)x0)[t] = make_float2(re0, re1);
    ((float2*)x1)[t] = make_float2(im0, im1);
}

// ---------------- Pass B: tap-pair correlation tensors -----------------------
__global__ __launch_bounds__(W_) void kb_corr(const float* __restrict__ e,
                                              const float* __restrict__ ws_r,
                                              float* __restrict__ ws) {
    const int c = threadIdx.x;        // column
    const int strip = blockIdx.x;
    const int pair = blockIdx.y;
    const int b = blockIdx.z;
    const float* imgs[3];
    imgs[0] = ws_r + WS_XIMG + ((size_t)b*2+0)*HW;
    imgs[1] = ws_r + WS_XIMG + ((size_t)b*2+1)*HW;
    imgs[2] = e + (size_t)b*HW;
    const int pa[6] = {0,1,0,0,1,2};
    const int pb[6] = {2,2,0,1,1,2};
    const float* A  = imgs[pa[pair]];
    const float* Bm = imgs[pb[pair]];

    __shared__ float lA[3][W_+2];
    __shared__ float lB[3][W_+2];
    if (c == 0) {
        #pragma unroll
        for (int s=0;s<3;s++){ lA[s][0]=0.f; lA[s][W_+1]=0.f; lB[s][0]=0.f; lB[s][W_+1]=0.f; }
    }
    float acc[9][9];
    #pragma unroll
    for (int i=0;i<9;i++)
        #pragma unroll
        for (int j=0;j<9;j++) acc[i][j]=0.f;

    const int r0 = strip * ROWS_PER;
    { // preload rows r0-1, r0
        int rr = r0 - 1;
        int slot = (r0 + 2) % 3;
        lA[slot][c+1] = (rr >= 0) ? A [rr*W_ + c] : 0.f;
        lB[slot][c+1] = (rr >= 0) ? Bm[rr*W_ + c] : 0.f;
        rr = r0; slot = r0 % 3;
        lA[slot][c+1] = A [rr*W_ + c];
        lB[slot][c+1] = Bm[rr*W_ + c];
    }
    for (int r = r0; r < r0 + ROWS_PER; ++r) {
        __syncthreads();                       // prior reads done
        int rr = r + 1;
        int slot = rr % 3;
        lA[slot][c+1] = (rr < H_) ? A [rr*W_ + c] : 0.f;
        lB[slot][c+1] = (rr < H_) ? Bm[rr*W_ + c] : 0.f;
        __syncthreads();                       // new row visible
        float aw[3][3], bw[3][3];
        #pragma unroll
        for (int i=0;i<3;i++){
            int s = (r - 1 + i + 3) % 3;
            #pragma unroll
            for (int k=0;k<3;k++){
                aw[i][k] = lA[s][c+k];
                bw[i][k] = lB[s][c+k];
            }
        }
        #pragma unroll
        for (int i=0;i<9;i++)
            #pragma unroll
            for (int j=0;j<9;j++)
                acc[i][j] += aw[i/3][i%3] * bw[j/3][j%3];
    }
    // wave reduce + atomic
    float* dst = ws + WS_CACC + ((size_t)(b*6 + pair))*81;
    #pragma unroll
    for (int i=0;i<9;i++)
        #pragma unroll
        for (int j=0;j<9;j++) {
            float v = acc[i][j];
            #pragma unroll
            for (int off=32; off>0; off>>=1) v += __shfl_down(v, off, 64);
            if ((threadIdx.x & 63) == 0)
                atomicAdd(dst + i*9 + j, v);
        }
}

// ---------------- Pass C: norms, Gram, softmax, fold into G ------------------
__global__ void kc_attn(const float* __restrict__ w_im1,
                        const float* __restrict__ w_im2,
                        const float* __restrict__ w_e,
                        const float* __restrict__ w_proj,
                        const float* __restrict__ a1,
                        float* __restrict__ ws) {
    const int b = blockIdx.x;
    const int tid = threadIdx.x;   // 384 threads
    const float* C   = ws + WS_CACC + (size_t)b*6*81;
    const float* D0  = C;
    const float* D1  = C + 81;
    const float* E00 = C + 162;
    const float* E01 = C + 243;
    const float* E11 = C + 324;
    const float* F   = C + 405;

    __shared__ float nk[192];
    __shared__ float P[192][24];
    __shared__ float Wm[2][192];

    float tmp1[9];
    float nq = 0.f;
    if (tid < 192) {
        const int j = tid;
        float Aq0[9], Aq1[9];
        const float w0 = w_im1[j*2+0], w1 = w_im1[j*2+1];
        #pragma unroll
        for (int t=0;t<9;t++){ float w2 = w_im2[j*9+t]; Aq0[t]=w0*w2; Aq1[t]=w1*w2; }
        #pragma unroll
        for (int u=0;u<9;u++){
            float s = 0.f;
            #pragma unroll
            for (int t=0;t<9;t++) s += Aq0[t]*D0[t*9+u] + Aq1[t]*D1[t*9+u];
            tmp1[u] = s;
        }
        float nq2 = 0.f;
        #pragma unroll
        for (int t=0;t<9;t++)
            #pragma unroll
            for (int u=0;u<9;u++)
                nq2 += Aq0[t]*Aq0[u]*E00[t*9+u] + Aq1[t]*Aq1[u]*E11[t*9+u]
                     + Aq0[t]*Aq1[u]*E01[t*9+u] + Aq1[t]*Aq0[u]*E01[u*9+t];
        nq = sqrtf(fmaxf(nq2, 0.f));
        float nk2 = 0.f;
        #pragma unroll
        for (int t=0;t<9;t++)
            #pragma unroll
            for (int u=0;u<9;u++)
                nk2 += w_e[j*9+t]*w_e[j*9+u]*F[t*9+u];
        nk[j] = sqrtf(fmaxf(nk2, 0.f));
    }
    __syncthreads();
    if (tid < 192) {
        const int j = tid, h = j/24;
        const float a1h = a1[h];
        const float inq = 1.f / fmaxf(nq, 1e-12f);
        float l[24]; float m = -1e30f;
        #pragma unroll
        for (int d=0; d<24; ++d) {
            const float* we = w_e + (h*24+d)*9;
            float s = 0.f;
            #pragma unroll
            for (int u=0;u<9;u++) s += tmp1[u]*we[u];
            s = s * a1h * inq / fmaxf(nk[h*24+d], 1e-12f);
            l[d] = s; m = fmaxf(m, s);
        }
        float sum = 0.f;
        #pragma unroll
        for (int d=0;d<24;d++){ float p = __expf(l[d]-m); l[d]=p; sum+=p; }
        const float isum = 1.f/sum;
        #pragma unroll
        for (int d=0;d<24;d++) P[j][d] = l[d]*isum;
    }
    __syncthreads();
    if (tid < 384) {
        const int pch = tid/192, xx = tid%192, h = xx/24, d = xx%24;
        float s = 0.f;
        #pragma unroll
        for (int c=0;c<24;c++) s += w_proj[pch*192 + h*24 + c] * P[h*24+c][d];
        Wm[pch][xx] = s;
    }
    __syncthreads();
    if (tid < 36) {
        const int pch = tid/18, rem = tid%18, r = rem/9, t9 = rem%9;
        float s = 0.f;
        for (int j=0;j<192;j++)
            s += Wm[pch][j] * w_im1[(192+j)*2 + r] * w_im2[(192+j)*9 + t9];
        ws[WS_G + b*36 + pch*18 + r*9 + t9] = s;
    }
}

// ---------------- Pass D: out = cmul(ximg + conv3x3(ximg,G), sens) -----------
__global__ void kd_out(const float* __restrict__ sens,
                       const float* __restrict__ ws,
                       float* __restrict__ out) {
    const int b = blockIdx.y;
    const int t = blockIdx.x*blockDim.x + threadIdx.x;  // pixel-pair
    if (t >= HW/2) return;
    const int p0 = 2*t;
    const int row = p0 / W_, col = p0 % W_;
    const float* gm = ws + WS_G + b*36;                 // uniform -> s_loads
    const float* X0 = ws + WS_XIMG + ((size_t)b*2+0)*HW;
    const float* X1 = ws + WS_XIMG + ((size_t)b*2+1)*HW;

    float n0[3][4], n1[3][4];
    #pragma unroll
    for (int i=0;i<3;i++){
        const int rr = row-1+i;
        const bool rok = (rr>=0 && rr<H_);
        #pragma unroll
        for (int k=0;k<4;k++){
            const int cc = col-1+k;
            const bool ok = rok && (cc>=0) && (cc<W_);
            n0[i][k] = ok ? X0[rr*W_+cc] : 0.f;
            n1[i][k] = ok ? X1[rr*W_+cc] : 0.f;
        }
    }
    float ore[2], oim[2];
    #pragma unroll
    for (int px=0; px<2; ++px) {
        float a0 = n0[1][1+px];   // + ximg (residual)
        float a1v = n1[1][1+px];
        #pragma unroll
        for (int i=0;i<3;i++)
            #pragma unroll
            for (int k=0;k<3;k++){
                const float v0 = n0[i][k+px], v1 = n1[i][k+px];
                a0  += gm[ 0 + i*3+k]*v0 + gm[ 9 + i*3+k]*v1;
                a1v += gm[18 + i*3+k]*v0 + gm[27 + i*3+k]*v1;
            }
        ore[px] = a0; oim[px] = a1v;
    }
    const float4* sp = (const float4*)(sens + (size_t)b*NCOIL*HW*2);
    float4* op = (float4*)(out + (size_t)b*NCOIL*HW*2);
    for (int c=0;c<NCOIL;c++){
        float4 sv = sp[(size_t)c*(HW/2)+t];
        float4 ov;
        ov.x = ore[0]*sv.x - oim[0]*sv.y;
        ov.y = ore[0]*sv.y + oim[0]*sv.x;
        ov.z = ore[1]*sv.z - oim[1]*sv.w;
        ov.w = ore[1]*sv.w + oim[1]*sv.z;
        op[(size_t)c*(HW/2)+t] = ov;
    }
}

extern "C" void kernel_launch(void* const* d_in, const int* in_sizes, int n_in,
                              void* d_out, int out_size, void* d_ws, size_t ws_size,
                              hipStream_t stream) {
    const float* x      = (const float*)d_in[0];
    const float* e      = (const float*)d_in[1];
    const float* sens   = (const float*)d_in[2];
    const float* w_im1  = (const float*)d_in[3];
    const float* w_im2  = (const float*)d_in[4];
    const float* w_e    = (const float*)d_in[5];
    const float* w_proj = (const float*)d_in[6];
    const float* a1     = (const float*)d_in[7];
    float* ws  = (float*)d_ws;
    float* out = (float*)d_out;

    dim3 gA(HW/2/256, B_);
    ka_coil_reduce<<<gA, 256, 0, stream>>>(x, sens, ws);
    dim3 gB(STRIPS, 6, B_);
    kb_corr<<<gB, W_, 0, stream>>>(e, ws, ws);
    kc_attn<<<dim3(B_), 384, 0, stream>>>(w_im1, w_im2, w_e, w_proj, a1, ws);
    dim3 gD(HW/2/256, B_);
    kd_out<<<gD, 256, 0, stream>>>(sens, ws, out);
}

// Round 2
// 473.429 us; speedup vs baseline: 1.2077x; 1.2077x over previous
//
#include <hip/hip_runtime.h>
#include <math.h>

#define B_     8
#define NCOIL  16
#define H_     384
#define W_     384
#define HW     (H_*W_)

// kb tiling: 16 strips of 24 rows; block = 64 col-groups x 4 row-groups
#define KB_STRIPS 16
#define KB_TC     6              // cols per thread (64*6 = 384)
#define KB_RPT    6              // rows per thread (4 rg * 6 = 24 = strip)

// ws layout (floats):
//   [0, 3888)            Cacc[b][6][81]  pair order: x0e, x1e, x0x0, x0x1, x1x1, ee
//   [3888, 4176)         G[b][2][2][9]
//   [4224, 4224+2359296) ximg[b][2][HW]
#define WS_CACC 0
#define WS_G    3888
#define WS_XIMG 4224

// ---------------- Pass A: coil-combine  ximg = sum_c x * conj(sens) ----------
__global__ void ka_coil_reduce(const float* __restrict__ x,
                               const float* __restrict__ sens,
                               float* __restrict__ ws) {
    int b = blockIdx.y;
    int t = blockIdx.x * blockDim.x + threadIdx.x;   // pixel-pair index
    // block 0 of each b also zeroes that b's correlation accumulators
    if (blockIdx.x == 0) {
        for (int i = threadIdx.x; i < 6*81; i += blockDim.x)
            ws[WS_CACC + b*6*81 + i] = 0.f;
    }
    if (t >= HW/2) return;
    const float4* xp = (const float4*)(x    + (size_t)b*NCOIL*HW*2);
    const float4* sp = (const float4*)(sens + (size_t)b*NCOIL*HW*2);
    float re0=0.f, im0=0.f, re1=0.f, im1=0.f;
    #pragma unroll 4
    for (int c = 0; c < NCOIL; ++c) {
        float4 xv = xp[(size_t)c*(HW/2) + t];
        float4 sv = sp[(size_t)c*(HW/2) + t];
        re0 += xv.x*sv.x + xv.y*sv.y;      // x * conj(s): re
        im0 += xv.y*sv.x - xv.x*sv.y;      // im
        re1 += xv.z*sv.z + xv.w*sv.w;
        im1 += xv.w*sv.z - xv.z*sv.w;
    }
    float* x0 = ws + WS_XIMG + ((size_t)b*2+0)*HW;
    float* x1 = ws + WS_XIMG + ((size_t)b*2+1)*HW;
    ((float2*)x0)[t] = make_float2(re0, re1);
    ((float2*)x1)[t] = make_float2(im0, im1);
}

// ---------------- Pass B: tap-pair correlation tensors -----------------------
// Each thread owns a KB_TC-wide x KB_RPT-tall pixel patch; rolling 3x(TC+2)
// register windows loaded directly from global (L2-resident). No barriers in
// the main loop; wave shfl-reduce + 4-way LDS combine -> 81 atomics/block.
__device__ __forceinline__ void kb_load_row(const float* __restrict__ img,
                                            int r, int c0, float* dst) {
    if (r < 0 || r >= H_) {
        #pragma unroll
        for (int k = 0; k < KB_TC+2; ++k) dst[k] = 0.f;
        return;
    }
    const float* p = img + r*W_ + (c0 - 1);
    #pragma unroll
    for (int k = 0; k < KB_TC+2; ++k) {
        const int cc = c0 - 1 + k;
        dst[k] = (cc >= 0 && cc < W_) ? p[k] : 0.f;
    }
}

__global__ __launch_bounds__(256) void kb_corr(const float* __restrict__ e,
                                               const float* __restrict__ ws_r,
                                               float* __restrict__ ws) {
    const int tid  = threadIdx.x;
    const int cg   = tid & 63;          // column group (lane)
    const int rg   = tid >> 6;          // row group == wave id, 0..3
    const int strip= blockIdx.x;        // 0..KB_STRIPS-1
    const int pair = blockIdx.y;        // 0..5
    const int b    = blockIdx.z;

    const float* imgs[3];
    imgs[0] = ws_r + WS_XIMG + ((size_t)b*2+0)*HW;
    imgs[1] = ws_r + WS_XIMG + ((size_t)b*2+1)*HW;
    imgs[2] = e + (size_t)b*HW;
    const int pa[6] = {0,1,0,0,1,2};
    const int pb[6] = {2,2,0,1,1,2};
    const float* __restrict__ A  = imgs[pa[pair]];
    const float* __restrict__ Bm = imgs[pb[pair]];

    const int c0      = cg * KB_TC;
    const int r_start = strip * (KB_RPT*4) + rg * KB_RPT;

    float acc[81];
    #pragma unroll
    for (int i = 0; i < 81; ++i) acc[i] = 0.f;

    float wA[3][KB_TC+2], wB[3][KB_TC+2];
    kb_load_row(A,  r_start-1, c0, wA[0]);
    kb_load_row(Bm, r_start-1, c0, wB[0]);
    kb_load_row(A,  r_start,   c0, wA[1]);
    kb_load_row(Bm, r_start,   c0, wB[1]);

    for (int r = r_start; r < r_start + KB_RPT; ++r) {
        kb_load_row(A,  r+1, c0, wA[2]);
        kb_load_row(Bm, r+1, c0, wB[2]);
        #pragma unroll
        for (int m = 0; m < KB_TC; ++m) {
            #pragma unroll
            for (int t = 0; t < 9; ++t) {
                const float av = wA[t/3][m + t%3];
                #pragma unroll
                for (int u = 0; u < 9; ++u)
                    acc[t*9+u] += av * wB[u/3][m + u%3];
            }
        }
        #pragma unroll
        for (int k = 0; k < KB_TC+2; ++k) {
            wA[0][k] = wA[1][k]; wA[1][k] = wA[2][k];
            wB[0][k] = wB[1][k]; wB[1][k] = wB[2][k];
        }
    }

    __shared__ float red[4][81];
    #pragma unroll
    for (int i = 0; i < 81; ++i) {
        float v = acc[i];
        v += __shfl_xor(v, 1);  v += __shfl_xor(v, 2);  v += __shfl_xor(v, 4);
        v += __shfl_xor(v, 8);  v += __shfl_xor(v, 16); v += __shfl_xor(v, 32);
        if (cg == 0) red[rg][i] = v;
    }
    __syncthreads();
    if (tid < 81) {
        float* dst = ws + WS_CACC + ((size_t)(b*6 + pair))*81;
        atomicAdd(dst + tid, red[0][tid] + red[1][tid] + red[2][tid] + red[3][tid]);
    }
}

// ---------------- Pass C: norms, Gram, softmax, fold into G ------------------
__global__ void kc_attn(const float* __restrict__ w_im1,
                        const float* __restrict__ w_im2,
                        const float* __restrict__ w_e,
                        const float* __restrict__ w_proj,
                        const float* __restrict__ a1,
                        float* __restrict__ ws) {
    const int b = blockIdx.x;
    const int tid = threadIdx.x;   // 384 threads
    const float* C   = ws + WS_CACC + (size_t)b*6*81;
    const float* D0  = C;
    const float* D1  = C + 81;
    const float* E00 = C + 162;
    const float* E01 = C + 243;
    const float* E11 = C + 324;
    const float* F   = C + 405;

    __shared__ float nk[192];
    __shared__ float P[192][24];
    __shared__ float Wm[2][192];

    float tmp1[9];
    float nq = 0.f;
    if (tid < 192) {
        const int j = tid;
        float Aq0[9], Aq1[9];
        const float w0 = w_im1[j*2+0], w1 = w_im1[j*2+1];
        #pragma unroll
        for (int t=0;t<9;t++){ float w2 = w_im2[j*9+t]; Aq0[t]=w0*w2; Aq1[t]=w1*w2; }
        #pragma unroll
        for (int u=0;u<9;u++){
            float s = 0.f;
            #pragma unroll
            for (int t=0;t<9;t++) s += Aq0[t]*D0[t*9+u] + Aq1[t]*D1[t*9+u];
            tmp1[u] = s;
        }
        float nq2 = 0.f;
        #pragma unroll
        for (int t=0;t<9;t++)
            #pragma unroll
            for (int u=0;u<9;u++)
                nq2 += Aq0[t]*Aq0[u]*E00[t*9+u] + Aq1[t]*Aq1[u]*E11[t*9+u]
                     + Aq0[t]*Aq1[u]*E01[t*9+u] + Aq1[t]*Aq0[u]*E01[u*9+t];
        nq = sqrtf(fmaxf(nq2, 0.f));
        float nk2 = 0.f;
        #pragma unroll
        for (int t=0;t<9;t++)
            #pragma unroll
            for (int u=0;u<9;u++)
                nk2 += w_e[j*9+t]*w_e[j*9+u]*F[t*9+u];
        nk[j] = sqrtf(fmaxf(nk2, 0.f));
    }
    __syncthreads();
    if (tid < 192) {
        const int j = tid, h = j/24;
        const float a1h = a1[h];
        const float inq = 1.f / fmaxf(nq, 1e-12f);
        float l[24]; float m = -1e30f;
        #pragma unroll
        for (int d=0; d<24; ++d) {
            const float* we = w_e + (h*24+d)*9;
            float s = 0.f;
            #pragma unroll
            for (int u=0;u<9;u++) s += tmp1[u]*we[u];
            s = s * a1h * inq / fmaxf(nk[h*24+d], 1e-12f);
            l[d] = s; m = fmaxf(m, s);
        }
        float sum = 0.f;
        #pragma unroll
        for (int d=0;d<24;d++){ float p = __expf(l[d]-m); l[d]=p; sum+=p; }
        const float isum = 1.f/sum;
        #pragma unroll
        for (int d=0;d<24;d++) P[j][d] = l[d]*isum;
    }
    __syncthreads();
    if (tid < 384) {
        const int pch = tid/192, xx = tid%192, h = xx/24, d = xx%24;
        float s = 0.f;
        #pragma unroll
        for (int c=0;c<24;c++) s += w_proj[pch*192 + h*24 + c] * P[h*24+c][d];
        Wm[pch][xx] = s;
    }
    __syncthreads();
    if (tid < 36) {
        const int pch = tid/18, rem = tid%18, r = rem/9, t9 = rem%9;
        float s = 0.f;
        for (int j=0;j<192;j++)
            s += Wm[pch][j] * w_im1[(192+j)*2 + r] * w_im2[(192+j)*9 + t9];
        ws[WS_G + b*36 + pch*18 + r*9 + t9] = s;
    }
}

// ---------------- Pass D: out = cmul(ximg + conv3x3(ximg,G), sens) -----------
__global__ void kd_out(const float* __restrict__ sens,
                       const float* __restrict__ ws,
                       float* __restrict__ out) {
    const int b = blockIdx.y;
    const int t = blockIdx.x*blockDim.x + threadIdx.x;  // pixel-pair
    if (t >= HW/2) return;
    const int p0 = 2*t;
    const int row = p0 / W_, col = p0 % W_;
    const float* gm = ws + WS_G + b*36;                 // uniform -> s_loads
    const float* X0 = ws + WS_XIMG + ((size_t)b*2+0)*HW;
    const float* X1 = ws + WS_XIMG + ((size_t)b*2+1)*HW;

    float n0[3][4], n1[3][4];
    #pragma unroll
    for (int i=0;i<3;i++){
        const int rr = row-1+i;
        const bool rok = (rr>=0 && rr<H_);
        #pragma unroll
        for (int k=0;k<4;k++){
            const int cc = col-1+k;
            const bool ok = rok && (cc>=0) && (cc<W_);
            n0[i][k] = ok ? X0[rr*W_+cc] : 0.f;
            n1[i][k] = ok ? X1[rr*W_+cc] : 0.f;
        }
    }
    float ore[2], oim[2];
    #pragma unroll
    for (int px=0; px<2; ++px) {
        float a0 = n0[1][1+px];   // + ximg (residual)
        float a1v = n1[1][1+px];
        #pragma unroll
        for (int i=0;i<3;i++)
            #pragma unroll
            for (int k=0;k<3;k++){
                const float v0 = n0[i][k+px], v1 = n1[i][k+px];
                a0  += gm[ 0 + i*3+k]*v0 + gm[ 9 + i*3+k]*v1;
                a1v += gm[18 + i*3+k]*v0 + gm[27 + i*3+k]*v1;
            }
        ore[px] = a0; oim[px] = a1v;
    }
    const float4* sp = (const float4*)(sens + (size_t)b*NCOIL*HW*2);
    float4* op = (float4*)(out + (size_t)b*NCOIL*HW*2);
    for (int c=0;c<NCOIL;c++){
        float4 sv = sp[(size_t)c*(HW/2)+t];
        float4 ov;
        ov.x = ore[0]*sv.x - oim[0]*sv.y;
        ov.y = ore[0]*sv.y + oim[0]*sv.x;
        ov.z = ore[1]*sv.z - oim[1]*sv.w;
        ov.w = ore[1]*sv.w + oim[1]*sv.z;
        op[(size_t)c*(HW/2)+t] = ov;
    }
}

extern "C" void kernel_launch(void* const* d_in, const int* in_sizes, int n_in,
                              void* d_out, int out_size, void* d_ws, size_t ws_size,
                              hipStream_t stream) {
    const float* x      = (const float*)d_in[0];
    const float* e      = (const float*)d_in[1];
    const float* sens   = (const float*)d_in[2];
    const float* w_im1  = (const float*)d_in[3];
    const float* w_im2  = (const float*)d_in[4];
    const float* w_e    = (const float*)d_in[5];
    const float* w_proj = (const float*)d_in[6];
    const float* a1     = (const float*)d_in[7];
    float* ws  = (float*)d_ws;
    float* out = (float*)d_out;

    dim3 gA(HW/2/256, B_);
    ka_coil_reduce<<<gA, 256, 0, stream>>>(x, sens, ws);
    dim3 gB(KB_STRIPS, 6, B_);
    kb_corr<<<gB, 256, 0, stream>>>(e, ws, ws);
    kc_attn<<<dim3(B_), 384, 0, stream>>>(w_im1, w_im2, w_e, w_proj, a1, ws);
    dim3 gD(HW/2/256, B_);
    kd_out<<<gD, 256, 0, stream>>>(sens, ws, out);
}